// Round 13
// baseline (189.082 us; speedup 1.0000x reference)
//
#include <hip/hip_runtime.h>
#include <hip/hip_bf16.h>

#define BB 2
#define CC 512
#define GG 32
#define NN 4096
#define EPSV 1e-6f

typedef __attribute__((ext_vector_type(4))) float f32x4;
typedef __attribute__((ext_vector_type(8))) short s16x8;
typedef __attribute__((ext_vector_type(4))) short s16x4;

__device__ __forceinline__ ushort f2bf(float f){
  union { float f; unsigned u; } v; v.f = f;
  unsigned r = v.u + 0x7fffu + ((v.u >> 16) & 1u);
  return (ushort)(r >> 16);
}
__device__ __forceinline__ short f2bfs(float f){ return (short)f2bf(f); }
__device__ __forceinline__ float b2f(ushort u){
  union { unsigned u; float f; } v; v.u = ((unsigned)u) << 16; return v.f;
}

__device__ __forceinline__ f32x4 mfma16(s16x8 a, s16x8 b, f32x4 c){
  return __builtin_amdgcn_mfma_f32_16x16x32_bf16(a, b, c, 0, 0, 0);
}

#define GLOAD_LDS16(g, l) __builtin_amdgcn_global_load_lds( \
    (const __attribute__((address_space(1))) void*)(g),     \
    (__attribute__((address_space(3))) void*)(l), 16, 0, 0)

// ---------------- weight fp32 -> bf16 ----------------
__global__ __launch_bounds__(256) void k_convert_w(const float* __restrict__ wq, const float* __restrict__ wk,
                                                   const float* __restrict__ wv, const float* __restrict__ wp,
                                                   ushort* __restrict__ wbf){
  int idx = blockIdx.x * 256 + threadIdx.x;
  const float* srcs[4] = {wq, wk, wv, wp};
  #pragma unroll
  for (int m = 0; m < 4; m++){
    float4 v = reinterpret_cast<const float4*>(srcs[m])[idx];
    ushort4 o; o.x = f2bf(v.x); o.y = f2bf(v.y); o.z = f2bf(v.z); o.w = f2bf(v.w);
    reinterpret_cast<ushort4*>(wbf + (size_t)m * CC * CC)[idx] = o;
  }
}

// ---------------- GroupNorm stats ----------------
__global__ __launch_bounds__(256) void k_gn_stats(const float* __restrict__ x, float* __restrict__ stats){
  int bg = blockIdx.x;  // 0..63
  const float* p = x + (size_t)bg * (16 * NN);
  float s = 0.f, ss = 0.f;
  for (int i = threadIdx.x; i < 16 * NN / 4; i += 256){
    float4 v = reinterpret_cast<const float4*>(p)[i];
    s  += v.x + v.y + v.z + v.w;
    ss += v.x*v.x + v.y*v.y + v.z*v.z + v.w*v.w;
  }
  #pragma unroll
  for (int off = 32; off; off >>= 1){ s += __shfl_down(s, off); ss += __shfl_down(ss, off); }
  __shared__ float rs_[4], rss_[4];
  int w = threadIdx.x >> 6, lane = threadIdx.x & 63;
  if (lane == 0){ rs_[w] = s; rss_[w] = ss; }
  __syncthreads();
  if (threadIdx.x == 0){
    float S = rs_[0] + rs_[1] + rs_[2] + rs_[3];
    float SS = rss_[0] + rss_[1] + rss_[2] + rss_[3];
    float inv = 1.0f / (16.0f * NN);
    float mean = S * inv;
    float var = SS * inv - mean * mean;
    stats[bg * 2 + 0] = mean;
    stats[bg * 2 + 1] = rsqrtf(var + EPSV);
  }
}

// ---------------- GN apply + transpose: x[b][c][n] -> hf_t[b][n][c] bf16 ----------------
__global__ __launch_bounds__(256) void k_gn_apply(const float* __restrict__ x, const float* __restrict__ gsc,
                                                  const float* __restrict__ gbi, const float* __restrict__ stats,
                                                  ushort* __restrict__ hf){
  __shared__ ushort tr[32][520];
  int b = blockIdx.y;
  int nb = blockIdx.x * 32;
  int t = threadIdx.x;
  int n = t & 31, cr = t >> 5;
  const float* xb = x + (size_t)b * CC * NN;
  for (int c0 = 0; c0 < CC; c0 += 8){
    int c = c0 + cr;
    float mean = stats[(b * GG + (c >> 4)) * 2 + 0];
    float rstd = stats[(b * GG + (c >> 4)) * 2 + 1];
    float v = xb[(size_t)c * NN + nb + n];
    tr[n][c] = f2bf((v - mean) * rstd * gsc[c] + gbi[c]);
  }
  __syncthreads();
  ushort* out = hf + ((size_t)b * NN + nb) * CC;
  int c8 = (t & 63) * 8;
  int nrow0 = t >> 6;
  #pragma unroll
  for (int i = 0; i < 8; i++){
    int nr = nrow0 + i * 4;
    *reinterpret_cast<s16x8*>(&out[(size_t)nr * CC + c8]) =
      *reinterpret_cast<const s16x8*>(&tr[nr][c8]);
  }
}

// ---------------- fused QKV GEMM v2: 64o x 128n tile, BK=32, dbuf gload_lds ----------------
__global__ __launch_bounds__(256, 3) void k_gemm_qkv2(const ushort* __restrict__ W, const ushort* __restrict__ Bt,
                                                      const float* __restrict__ bq, const float* __restrict__ bk,
                                                      const float* __restrict__ bv,
                                                      ushort* __restrict__ qo, ushort* __restrict__ ko,
                                                      ushort* __restrict__ vo, float rs){
  __shared__ __align__(16) char smem[40960];   // dbuf 2x20KB staging; epilogue Ve [64][136] bf16 overlays
  __shared__ float bl[3][64];
  int b = blockIdx.z, ob = blockIdx.y * 64, nb = blockIdx.x * 128;
  int t = threadIdx.x, w = t >> 6, l = t & 63;
  int lr = l & 15, lk = l >> 4;
  int wo = (w >> 1) * 32, wn = (w & 1) * 64;
  if (t < 64){ bl[0][t] = bq[ob + t]; bl[1][t] = bk[ob + t]; bl[2][t] = bv[ob + t]; }
  const ushort* Bp = Bt + ((size_t)b * NN + nb) * CC;
  const ushort* Wp = W + (size_t)ob * CC;
  int srow = l >> 2;                                         // row within 16-row group
  int schunk = (l & 3) ^ ((l >> 2) & 3) ^ ((l >> 4) & 3);    // swizzled 16B chunk of 64B row
  int xs = (lk ^ (lr & 3) ^ ((lr >> 2) & 3)) * 8;

#define STAGE_QKV(BUF, K0)                                                               \
  {                                                                                      \
    ushort* As_ = (ushort*)(smem + (BUF) * 20480);                                       \
    ushort* Bs_ = As_ + 6144;                                                            \
    _Pragma("unroll")                                                                    \
    for (int tt = 0; tt < 5; tt++){                                                      \
      int inst = w * 5 + tt;                                                             \
      if (inst < 12){                                                                    \
        int m = inst >> 2, sub = inst & 3;                                               \
        const ushort* src = Wp + (size_t)m * CC * CC + (size_t)(sub * 16 + srow) * CC + (K0) + schunk * 8; \
        GLOAD_LDS16(src, As_ + m * 2048 + sub * 512);                                    \
      } else {                                                                           \
        int q = inst - 12;                                                               \
        const ushort* src = Bp + (size_t)(q * 16 + srow) * CC + (K0) + schunk * 8;       \
        GLOAD_LDS16(src, Bs_ + q * 512);                                                 \
      }                                                                                  \
    }                                                                                    \
  }

  f32x4 acc[3][2][4] = {};
  STAGE_QKV(0, 0)
  __syncthreads();
  for (int s16 = 0; s16 < 16; s16++){
    if (s16 < 15) STAGE_QKV((s16 + 1) & 1, (s16 + 1) * 32)
    const ushort* As = (const ushort*)(smem + (s16 & 1) * 20480);
    const ushort* Bs = As + 6144;
    s16x8 bf[4];
    #pragma unroll
    for (int sn = 0; sn < 4; sn++)
      bf[sn] = *(const s16x8*)&Bs[(wn + sn * 16 + lr) * 32 + xs];
    #pragma unroll
    for (int m = 0; m < 3; m++){
      s16x8 a0 = *(const s16x8*)&As[m * 2048 + (wo + lr) * 32 + xs];
      s16x8 a1 = *(const s16x8*)&As[m * 2048 + (wo + 16 + lr) * 32 + xs];
      #pragma unroll
      for (int sn = 0; sn < 4; sn++){
        acc[m][0][sn] = mfma16(a0, bf[sn], acc[m][0][sn]);
        acc[m][1][sn] = mfma16(a1, bf[sn], acc[m][1][sn]);
      }
    }
    __syncthreads();
  }
#undef STAGE_QKV
  // q, k epilogue: transposed [n][o]
  #pragma unroll
  for (int m = 0; m < 2; m++){
    ushort* dst = (m == 0) ? qo : ko;
    float scl = (m == 0) ? rs : 1.0f;
    #pragma unroll
    for (int so = 0; so < 2; so++)
      #pragma unroll
      for (int sn = 0; sn < 4; sn++){
        int o0 = wo + so * 16 + lk * 4;
        int n  = nb + wn + sn * 16 + lr;
        s16x4 pv;
        #pragma unroll
        for (int r = 0; r < 4; r++) pv[r] = f2bfs((acc[m][so][sn][r] + bl[m][o0 + r]) * scl);
        *reinterpret_cast<s16x4*>(&dst[((size_t)b * NN + n) * CC + ob + o0]) = pv;
      }
  }
  // v epilogue: [o][n] via LDS transpose
  ushort* Ve = (ushort*)smem;   // [64][136]
  #pragma unroll
  for (int so = 0; so < 2; so++)
    #pragma unroll
    for (int sn = 0; sn < 4; sn++){
      int o0 = wo + so * 16 + lk * 4;
      int ncl = wn + sn * 16 + lr;
      #pragma unroll
      for (int r = 0; r < 4; r++) Ve[(o0 + r) * 136 + ncl] = f2bf(acc[2][so][sn][r] + bl[2][o0 + r]);
    }
  __syncthreads();
  {
    int row = t >> 2, cs = (t & 3) * 32;
    ushort* dst = &vo[((size_t)b * CC + ob + row) * NN + nb + cs];
    #pragma unroll
    for (int k = 0; k < 4; k++)
      *(s16x8*)&dst[k * 8] = *(const s16x8*)&Ve[row * 136 + cs + k * 8];
  }
}

// ---------------- S GEMM v5: 256x256, BK=64, dbuf, counted-vmcnt barrier schedule ----------------
// Key change vs v4: the per-step barrier no longer drains the just-issued next-tile loads.
// Per wave: 8 gload_lds per stage. s_waitcnt vmcnt(8) waits only for the PREVIOUS stage's
// loads (in-order per-wave completion); barrier then guarantees all waves' current buf done.
__global__ __launch_bounds__(512, 2) void k_gemm_s(const ushort* __restrict__ qt, const ushort* __restrict__ kt,
                                                   ushort* __restrict__ P, float* __restrict__ part){
  extern __shared__ __align__(16) char smem[];
  int lin = blockIdx.x + 16 * blockIdx.y + 256 * blockIdx.z;   // 0..511
  int tt0 = (lin & 7) * 64 + (lin >> 3);
  int jblk = tt0 & 15;
  int pair = tt0 >> 4;          // 0..31
  int b = pair >> 4;            // 0..1
  int j0 = jblk * 256, i0 = (pair & 15) * 256;
  int t = threadIdx.x, w = t >> 6, l = t & 63;
  int lr = l & 15, lk = l >> 4;
  int wj2 = w >> 2, wi4 = w & 3;     // wave tile: j in [wj2*128, +128), i in [wi4*64, +64)
  const ushort* kb = kt + ((size_t)b * NN + j0) * CC;
  const ushort* qb = qt + ((size_t)b * NN + i0) * CC;
  int srow = l >> 3;                       // row within 8-row group
  int schunk = (l & 7) ^ srow;             // swizzled 16B chunk within 128B row

#define STAGE_S(BUF, K0)                                                          \
  {                                                                               \
    ushort* Ks_ = (ushort*)(smem + (BUF) * 32768);                                \
    ushort* Qs_ = (ushort*)(smem + 65536 + (BUF) * 32768);                        \
    _Pragma("unroll")                                                             \
    for (int tt = 0; tt < 8; tt++){                                               \
      int inst = w * 8 + tt;                                                      \
      if (inst < 32){                                                             \
        const ushort* src = kb + (size_t)(inst * 8 + srow) * CC + (K0) + schunk * 8; \
        GLOAD_LDS16(src, Ks_ + inst * 512);                                       \
      } else {                                                                    \
        int g = inst - 32;                                                        \
        const ushort* src = qb + (size_t)(g * 8 + srow) * CC + (K0) + schunk * 8; \
        GLOAD_LDS16(src, Qs_ + g * 512);                                          \
      }                                                                           \
    }                                                                             \
  }

  f32x4 acc[8][4] = {};
  STAGE_S(0, 0)                     // 8 loads/wave in flight
  for (int s8 = 0; s8 < 8; s8++){
    if (s8 < 7){
      STAGE_S((s8 + 1) & 1, (s8 + 1) * 64)               // +8 loads/wave (next tile)
      asm volatile("s_waitcnt vmcnt(8)" ::: "memory");   // wait ONLY for current tile's 8
    } else {
      asm volatile("s_waitcnt vmcnt(0)" ::: "memory");
    }
    __builtin_amdgcn_s_barrier();          // all waves: current buf fully written
    __builtin_amdgcn_sched_barrier(0);     // fence: no ds_read hoisted above (rule #18)
    const ushort* Ks = (const ushort*)(smem + (s8 & 1) * 32768);
    const ushort* Qs = (const ushort*)(smem + 65536 + (s8 & 1) * 32768);
    #pragma unroll
    for (int kk = 0; kk < 2; kk++){
      int xs = ((kk * 4 + lk) ^ (lr & 7)) * 8;
      s16x8 bf[4];
      #pragma unroll
      for (int si = 0; si < 4; si++)
        bf[si] = *(const s16x8*)&Qs[(wi4 * 64 + si * 16 + lr) * 64 + xs];
      #pragma unroll
      for (int sj = 0; sj < 8; sj++){
        s16x8 a = *(const s16x8*)&Ks[(wj2 * 128 + sj * 16 + lr) * 64 + xs];
        #pragma unroll
        for (int si = 0; si < 4; si++)
          acc[sj][si] = mfma16(a, bf[si], acc[sj][si]);
      }
    }
    asm volatile("s_waitcnt lgkmcnt(0)" ::: "memory");   // all LDS reads landed in regs
    __builtin_amdgcn_s_barrier();          // safe to overwrite this buf next iter
    __builtin_amdgcn_sched_barrier(0);
  }
#undef STAGE_S
  // epilogue: exp2 + fused row-sum partials + P write via 2-pass LDS transpose
  ushort* Pe = (ushort*)smem;   // [128 i][264 j] per pass
  float rsum[4] = {0.f, 0.f, 0.f, 0.f};
  #pragma unroll
  for (int pass = 0; pass < 2; pass++){
    if ((wi4 >> 1) == pass){
      #pragma unroll
      for (int sj = 0; sj < 8; sj++)
        #pragma unroll
        for (int si = 0; si < 4; si++){
          int il = (wi4 & 1) * 64 + si * 16 + lr;     // row within this 128-i half
          int jl = wj2 * 128 + sj * 16 + lk * 4;
          s16x4 pk;
          #pragma unroll
          for (int r = 0; r < 4; r++){
            float e = __builtin_amdgcn_exp2f(acc[sj][si][r]);   // raw v_exp_f32 (args bounded)
            pk[r] = f2bfs(e);
            rsum[si] += e;
          }
          *(s16x4*)&Pe[il * 264 + jl] = pk;
        }
    }
    __syncthreads();
    {
      int row = t >> 2, cs = (t & 3) * 64;
      ushort* dst = P + ((size_t)b * NN + i0 + pass * 128 + row) * NN + j0 + cs;
      #pragma unroll
      for (int k = 0; k < 8; k++)
        *(s16x8*)&dst[k * 8] = *(const s16x8*)&Pe[row * 264 + cs + k * 8];
    }
    __syncthreads();   // Pe reused by next pass
  }
  // partial row sums: reduce lk via shfl
  #pragma unroll
  for (int si = 0; si < 4; si++){
    float s = rsum[si];
    s += __shfl_xor(s, 16);
    s += __shfl_xor(s, 32);
    if (lk == 0){
      int il = wi4 * 64 + si * 16 + lr;
      part[((size_t)b * NN + i0 + il) * 32 + jblk * 2 + wj2] = s;
    }
  }
}

// ---------------- combine partial row sums (32/row) -> linv ----------------
__global__ __launch_bounds__(256) void k_rowsum2(const float* __restrict__ part, float* __restrict__ linv){
  int row = blockIdx.x * 4 + (threadIdx.x >> 6);   // 0..8191
  int l = threadIdx.x & 63;
  float s = (l < 32) ? part[(size_t)row * 32 + l] : 0.f;
  #pragma unroll
  for (int off = 32; off; off >>= 1) s += __shfl_down(s, off);
  if (l == 0) linv[row] = 1.0f / s;
}

// ---------------- O GEMM v2: counted-vmcnt barrier schedule (3 loads/wave/stage) ----------------
__global__ __launch_bounds__(512) void k_gemm_o(const ushort* __restrict__ P, const ushort* __restrict__ vv,
                                                const float* __restrict__ linv, ushort* __restrict__ ot){
  __shared__ __align__(16) char smem[49152];   // Vs[2][8KB] @0, Ps[2][16KB] @16KB; epilogue Oe 18432B overlays
  int lin = blockIdx.x + 8 * blockIdx.y + 256 * blockIdx.z;    // 0..511
  int tt0 = (lin & 7) * 64 + (lin >> 3);
  int cblk = tt0 & 7;
  int pair = tt0 >> 3;          // 0..63
  int b = pair >> 5;
  int c0 = cblk * 64, i0 = (pair & 31) * 128;
  int t = threadIdx.x, w = t >> 6, l = t & 63;
  int lr = l & 15, lk = l >> 4;
  int wi = (w >> 1) * 32, wc = (w & 1) * 32;
  const ushort* vb = vv + ((size_t)b * CC + c0) * NN;
  const ushort* pb = P + ((size_t)b * NN + i0) * NN;
  int srow = l >> 3;
  int schunk = (l & 7) ^ srow;

#define STAGE_O(BUF, K0)                                                          \
  {                                                                               \
    ushort* Vs_ = (ushort*)(smem + (BUF) * 8192);                                 \
    ushort* Ps_ = (ushort*)(smem + 16384 + (BUF) * 16384);                        \
    _Pragma("unroll")                                                             \
    for (int tt = 0; tt < 3; tt++){                                               \
      int inst = w * 3 + tt;                                                      \
      if (inst < 8){                                                              \
        const ushort* src = vb + (size_t)(inst * 8 + srow) * NN + (K0) + schunk * 8; \
        GLOAD_LDS16(src, Vs_ + inst * 512);                                       \
      } else {                                                                    \
        int q = inst - 8;                                                         \
        const ushort* src = pb + (size_t)(q * 8 + srow) * NN + (K0) + schunk * 8; \
        GLOAD_LDS16(src, Ps_ + q * 512);                                          \
      }                                                                           \
    }                                                                             \
  }

  f32x4 acc[2][2] = {};
  STAGE_O(0, 0)
  for (int s64 = 0; s64 < 64; s64++){
    if (s64 < 63){
      STAGE_O((s64 + 1) & 1, (s64 + 1) * 64)
      asm volatile("s_waitcnt vmcnt(3)" ::: "memory");   // wait only for current tile's 3
    } else {
      asm volatile("s_waitcnt vmcnt(0)" ::: "memory");
    }
    __builtin_amdgcn_s_barrier();
    __builtin_amdgcn_sched_barrier(0);
    const ushort* Vs = (const ushort*)(smem + (s64 & 1) * 8192);
    const ushort* Ps = (const ushort*)(smem + 16384 + (s64 & 1) * 16384);
    #pragma unroll
    for (int kk = 0; kk < 2; kk++){
      int xs = ((kk * 4 + lk) ^ (lr & 7)) * 8;
      s16x8 af[2], bf[2];
      af[0] = *(const s16x8*)&Vs[(wc + lr) * 64 + xs];
      af[1] = *(const s16x8*)&Vs[(wc + 16 + lr) * 64 + xs];
      bf[0] = *(const s16x8*)&Ps[(wi + lr) * 64 + xs];
      bf[1] = *(const s16x8*)&Ps[(wi + 16 + lr) * 64 + xs];
      acc[0][0] = mfma16(af[0], bf[0], acc[0][0]);
      acc[0][1] = mfma16(af[0], bf[1], acc[0][1]);
      acc[1][0] = mfma16(af[1], bf[0], acc[1][0]);
      acc[1][1] = mfma16(af[1], bf[1], acc[1][1]);
    }
    asm volatile("s_waitcnt lgkmcnt(0)" ::: "memory");
    __builtin_amdgcn_s_barrier();
    __builtin_amdgcn_sched_barrier(0);
  }
#undef STAGE_O
  ushort* Oe = (ushort*)smem;   // [128 i][72 c]
  #pragma unroll
  for (int si = 0; si < 2; si++){
    int il = wi + si * 16 + lr;
    float li = linv[(size_t)b * NN + i0 + il];
    #pragma unroll
    for (int sc = 0; sc < 2; sc++){
      int cl = wc + sc * 16 + lk * 4;
      s16x4 pk;
      #pragma unroll
      for (int r = 0; r < 4; r++) pk[r] = f2bfs(acc[sc][si][r] * li);
      *(s16x4*)&Oe[il * 72 + cl] = pk;
    }
  }
  __syncthreads();
  {
    int row = t >> 2, cs = (t & 3) * 16;
    ushort* dst = ot + ((size_t)b * NN + i0 + row) * CC + c0 + cs;
    #pragma unroll
    for (int k = 0; k < 2; k++)
      *(s16x8*)&dst[k * 8] = *(const s16x8*)&Oe[row * 72 + cs + k * 8];
  }
}

// ---------------- proj GEMM v2: 64o x 128n, BK=32, dbuf gload_lds; fp32 out + residual ----------------
__global__ __launch_bounds__(256, 3) void k_gemm_proj2(const ushort* __restrict__ A, const ushort* __restrict__ Bt,
                                                       const float* __restrict__ bias, float* __restrict__ o32,
                                                       const float* __restrict__ xres){
  __shared__ __align__(16) char smem[34048];   // dbuf 2x12KB staging; epilogue trf [64][133] f32 = 34048B
  __shared__ float bl[64];
  int b = blockIdx.z, ob = blockIdx.y * 64, nb = blockIdx.x * 128;
  int t = threadIdx.x, w = t >> 6, l = t & 63;
  int lr = l & 15, lk = l >> 4;
  int wo = (w >> 1) * 32, wn = (w & 1) * 64;
  if (t < 64) bl[t] = bias[ob + t];
  const ushort* Bp = Bt + ((size_t)b * NN + nb) * CC;
  const ushort* Ap = A + (size_t)ob * CC;
  int srow = l >> 2;
  int schunk = (l & 3) ^ ((l >> 2) & 3) ^ ((l >> 4) & 3);
  int xs = (lk ^ (lr & 3) ^ ((lr >> 2) & 3)) * 8;

#define STAGE_P2(BUF, K0)                                                         \
  {                                                                               \
    ushort* As_ = (ushort*)(smem + (BUF) * 12288);                                \
    ushort* Bs_ = As_ + 2048;                                                     \
    _Pragma("unroll")                                                             \
    for (int tt = 0; tt < 3; tt++){                                               \
      int inst = w * 3 + tt;                                                      \
      if (inst < 4){                                                              \
        const ushort* src = Ap + (size_t)(inst * 16 + srow) * CC + (K0) + schunk * 8; \
        GLOAD_LDS16(src, As_ + inst * 512);                                       \
      } else {                                                                    \
        int q = inst - 4;                                                         \
        const ushort* src = Bp + (size_t)(q * 16 + srow) * CC + (K0) + schunk * 8; \
        GLOAD_LDS16(src, Bs_ + q * 512);                                          \
      }                                                                           \
    }                                                                             \
  }

  f32x4 acc[2][4] = {};
  STAGE_P2(0, 0)
  __syncthreads();
  for (int s16 = 0; s16 < 16; s16++){
    if (s16 < 15) STAGE_P2((s16 + 1) & 1, (s16 + 1) * 32)
    const ushort* As = (const ushort*)(smem + (s16 & 1) * 12288);
    const ushort* Bs = As + 2048;
    s16x8 a0 = *(const s16x8*)&As[(wo + lr) * 32 + xs];
    s16x8 a1 = *(const s16x8*)&As[(wo + 16 + lr) * 32 + xs];
    #pragma unroll
    for (int sn = 0; sn < 4; sn++){
      s16x8 bf = *(const s16x8*)&Bs[(wn + sn * 16 + lr) * 32 + xs];
      acc[0][sn] = mfma16(a0, bf, acc[0][sn]);
      acc[1][sn] = mfma16(a1, bf, acc[1][sn]);
    }
    __syncthreads();
  }
#undef STAGE_P2
  float* trf = (float*)smem;   // [64][133]
  #pragma unroll
  for (int so = 0; so < 2; so++)
    #pragma unroll
    for (int sn = 0; sn < 4; sn++){
      int o0 = wo + so * 16 + lk * 4;
      int ncl = wn + sn * 16 + lr;
      #pragma unroll
      for (int r = 0; r < 4; r++) trf[(o0 + r) * 133 + ncl] = acc[so][sn][r] + bl[o0 + r];
    }
  __syncthreads();
  {
    int row = t >> 2, cs = (t & 3) * 32;
    size_t base = ((size_t)b * CC + ob + row) * NN + nb + cs;
    #pragma unroll
    for (int q = 0; q < 8; q++){
      float4 xv = *reinterpret_cast<const float4*>(&xres[base + q * 4]);
      float4 ov;
      ov.x = xv.x + trf[row * 133 + cs + q * 4 + 0];
      ov.y = xv.y + trf[row * 133 + cs + q * 4 + 1];
      ov.z = xv.z + trf[row * 133 + cs + q * 4 + 2];
      ov.w = xv.w + trf[row * 133 + cs + q * 4 + 3];
      *reinterpret_cast<float4*>(&o32[base + q * 4]) = ov;
    }
  }
}

extern "C" void kernel_launch(void* const* d_in, const int* in_sizes, int n_in,
                              void* d_out, int out_size, void* d_ws, size_t ws_size,
                              hipStream_t stream){
  const float* x   = (const float*)d_in[0];
  const float* gsc = (const float*)d_in[1];
  const float* gbi = (const float*)d_in[2];
  const float* wq  = (const float*)d_in[3];
  const float* bq  = (const float*)d_in[4];
  const float* wk  = (const float*)d_in[5];
  const float* bk  = (const float*)d_in[6];
  const float* wv  = (const float*)d_in[7];
  const float* bv  = (const float*)d_in[8];
  const float* wp  = (const float*)d_in[9];
  const float* bp  = (const float*)d_in[10];
  char* ws = (char*)d_ws;
  const size_t MB = 1024 * 1024;
  ushort* wbf  = (ushort*)ws;                    // [0,2MB): bf16 weights q|k|v|proj
  ushort* qtb  = (ushort*)(ws + 2 * MB);         // [2,10): q^T [b][n][c], pre-scaled rs*log2e
  ushort* ktb  = (ushort*)(ws + 10 * MB);        // [10,18): k^T [b][n][c]
  ushort* vvb  = (ushort*)(ws + 18 * MB);        // [18,26): v [b][c][n]
  ushort* hfb  = (ushort*)(ws + 26 * MB);        // [26,34): hf^T, later attn-out [b][n][c]
  ushort* Pbuf = (ushort*)(ws + 34 * MB);        // [34,98): P = exp2(S) bf16 [b][i][j]
  float* linv  = (float*)(ws + 98 * MB);         // [98MB, +32KB)
  float* stats = (float*)(ws + 98 * MB + 64 * 1024);  // 512 B
  float* part  = (float*)(ws + 26 * MB);         // 1MB partials in dead-hf window
  ushort* otb = hfb;

  const float rs = 0.044194173824159216f * 1.4426950408889634f;

  k_convert_w<<<256, 256, 0, stream>>>(wq, wk, wv, wp, wbf);
  k_gn_stats<<<64, 256, 0, stream>>>(x, stats);
  k_gn_apply<<<dim3(128, 2, 1), 256, 0, stream>>>(x, gsc, gbi, stats, hfb);
  k_gemm_qkv2<<<dim3(32, 8, 2), 256, 0, stream>>>(wbf, hfb, bq, bk, bv, qtb, ktb, vvb, rs);
  k_gemm_s<<<dim3(16, 16, 2), 512, 131072, stream>>>(qtb, ktb, Pbuf, part);
  k_rowsum2<<<2048, 256, 0, stream>>>(part, linv);
  k_gemm_o<<<dim3(8, 32, 2), 512, 0, stream>>>(Pbuf, vvb, linv, otb);
  k_gemm_proj2<<<dim3(32, 8, 2), 256, 0, stream>>>(wbf + 3 * CC * CC, otb, bp, (float*)d_out, x);
}

// Round 15
// 177.454 us; speedup vs baseline: 1.0655x; 1.0655x over previous
//
#include <hip/hip_runtime.h>
#include <hip/hip_bf16.h>

#define BB 2
#define CC 512
#define GG 32
#define NN 4096
#define EPSV 1e-6f

typedef __attribute__((ext_vector_type(4))) float f32x4;
typedef __attribute__((ext_vector_type(8))) short s16x8;
typedef __attribute__((ext_vector_type(4))) short s16x4;

__device__ __forceinline__ ushort f2bf(float f){
  union { float f; unsigned u; } v; v.f = f;
  unsigned r = v.u + 0x7fffu + ((v.u >> 16) & 1u);
  return (ushort)(r >> 16);
}
__device__ __forceinline__ short f2bfs(float f){ return (short)f2bf(f); }
__device__ __forceinline__ float b2f(ushort u){
  union { unsigned u; float f; } v; v.u = ((unsigned)u) << 16; return v.f;
}

__device__ __forceinline__ f32x4 mfma16(s16x8 a, s16x8 b, f32x4 c){
  return __builtin_amdgcn_mfma_f32_16x16x32_bf16(a, b, c, 0, 0, 0);
}

#define GLOAD_LDS16(g, l) __builtin_amdgcn_global_load_lds( \
    (const __attribute__((address_space(1))) void*)(g),     \
    (__attribute__((address_space(3))) void*)(l), 16, 0, 0)

// ---------------- weight fp32 -> bf16 ----------------
__global__ __launch_bounds__(256) void k_convert_w(const float* __restrict__ wq, const float* __restrict__ wk,
                                                   const float* __restrict__ wv, const float* __restrict__ wp,
                                                   ushort* __restrict__ wbf){
  int idx = blockIdx.x * 256 + threadIdx.x;
  const float* srcs[4] = {wq, wk, wv, wp};
  #pragma unroll
  for (int m = 0; m < 4; m++){
    float4 v = reinterpret_cast<const float4*>(srcs[m])[idx];
    ushort4 o; o.x = f2bf(v.x); o.y = f2bf(v.y); o.z = f2bf(v.z); o.w = f2bf(v.w);
    reinterpret_cast<ushort4*>(wbf + (size_t)m * CC * CC)[idx] = o;
  }
}

// ---------------- GroupNorm stats, 2-stage ----------------
// stage 1: 256 blocks (4.19M floats / 16384 per block); 4 chunks per (b,g) group
__global__ __launch_bounds__(256) void k_gn_stats1(const float* __restrict__ x, float* __restrict__ pstat){
  int blk = blockIdx.x;   // 0..255
  const float* p = x + (size_t)blk * 16384;
  float s = 0.f, ss = 0.f;
  for (int i = threadIdx.x; i < 4096; i += 256){
    float4 v = reinterpret_cast<const float4*>(p)[i];
    s  += v.x + v.y + v.z + v.w;
    ss += v.x*v.x + v.y*v.y + v.z*v.z + v.w*v.w;
  }
  #pragma unroll
  for (int off = 32; off; off >>= 1){ s += __shfl_down(s, off); ss += __shfl_down(ss, off); }
  __shared__ float rs_[4], rss_[4];
  int w = threadIdx.x >> 6, lane = threadIdx.x & 63;
  if (lane == 0){ rs_[w] = s; rss_[w] = ss; }
  __syncthreads();
  if (threadIdx.x == 0){
    pstat[blk * 2 + 0] = rs_[0] + rs_[1] + rs_[2] + rs_[3];
    pstat[blk * 2 + 1] = rss_[0] + rss_[1] + rss_[2] + rss_[3];
  }
}
// stage 2: 64 groups; combine 4 partials each
__global__ __launch_bounds__(64) void k_gn_stats2(const float* __restrict__ pstat, float* __restrict__ stats){
  int bg = blockIdx.x;
  int l = threadIdx.x;
  float s = 0.f, ss = 0.f;
  if (l < 4){ s = pstat[(bg * 4 + l) * 2]; ss = pstat[(bg * 4 + l) * 2 + 1]; }
  #pragma unroll
  for (int off = 2; off; off >>= 1){ s += __shfl_down(s, off); ss += __shfl_down(ss, off); }
  if (l == 0){
    float inv = 1.0f / (16.0f * NN);
    float mean = s * inv;
    float var = ss * inv - mean * mean;
    stats[bg * 2 + 0] = mean;
    stats[bg * 2 + 1] = rsqrtf(var + EPSV);
  }
}

// ---------------- GN apply + transpose: x[b][c][n] -> hf_t[b][n][c] bf16 ----------------
__global__ __launch_bounds__(256) void k_gn_apply(const float* __restrict__ x, const float* __restrict__ gsc,
                                                  const float* __restrict__ gbi, const float* __restrict__ stats,
                                                  ushort* __restrict__ hf){
  __shared__ ushort tr[32][520];
  int b = blockIdx.y;
  int nb = blockIdx.x * 32;
  int t = threadIdx.x;
  int n = t & 31, cr = t >> 5;
  const float* xb = x + (size_t)b * CC * NN;
  for (int c0 = 0; c0 < CC; c0 += 8){
    int c = c0 + cr;
    float mean = stats[(b * GG + (c >> 4)) * 2 + 0];
    float rstd = stats[(b * GG + (c >> 4)) * 2 + 1];
    float v = xb[(size_t)c * NN + nb + n];
    tr[n][c] = f2bf((v - mean) * rstd * gsc[c] + gbi[c]);
  }
  __syncthreads();
  ushort* out = hf + ((size_t)b * NN + nb) * CC;
  int c8 = (t & 63) * 8;
  int nrow0 = t >> 6;
  #pragma unroll
  for (int i = 0; i < 8; i++){
    int nr = nrow0 + i * 4;
    *reinterpret_cast<s16x8*>(&out[(size_t)nr * CC + c8]) =
      *reinterpret_cast<const s16x8*>(&tr[nr][c8]);
  }
}

// ---------------- fused QKV GEMM v2: 64o x 128n tile, BK=32, dbuf gload_lds ----------------
__global__ __launch_bounds__(256, 3) void k_gemm_qkv2(const ushort* __restrict__ W, const ushort* __restrict__ Bt,
                                                      const float* __restrict__ bq, const float* __restrict__ bk,
                                                      const float* __restrict__ bv,
                                                      ushort* __restrict__ qo, ushort* __restrict__ ko,
                                                      ushort* __restrict__ vo, float rs){
  __shared__ __align__(16) char smem[40960];   // dbuf 2x20KB staging; epilogue Ve [64][136] bf16 overlays
  __shared__ float bl[3][64];
  int b = blockIdx.z, ob = blockIdx.y * 64, nb = blockIdx.x * 128;
  int t = threadIdx.x, w = t >> 6, l = t & 63;
  int lr = l & 15, lk = l >> 4;
  int wo = (w >> 1) * 32, wn = (w & 1) * 64;
  if (t < 64){ bl[0][t] = bq[ob + t]; bl[1][t] = bk[ob + t]; bl[2][t] = bv[ob + t]; }
  const ushort* Bp = Bt + ((size_t)b * NN + nb) * CC;
  const ushort* Wp = W + (size_t)ob * CC;
  int srow = l >> 2;                                         // row within 16-row group
  int schunk = (l & 3) ^ ((l >> 2) & 3) ^ ((l >> 4) & 3);    // swizzled 16B chunk of 64B row
  int xs = (lk ^ (lr & 3) ^ ((lr >> 2) & 3)) * 8;

#define STAGE_QKV(BUF, K0)                                                               \
  {                                                                                      \
    ushort* As_ = (ushort*)(smem + (BUF) * 20480);                                       \
    ushort* Bs_ = As_ + 6144;                                                            \
    _Pragma("unroll")                                                                    \
    for (int tt = 0; tt < 5; tt++){                                                      \
      int inst = w * 5 + tt;                                                             \
      if (inst < 12){                                                                    \
        int m = inst >> 2, sub = inst & 3;                                               \
        const ushort* src = Wp + (size_t)m * CC * CC + (size_t)(sub * 16 + srow) * CC + (K0) + schunk * 8; \
        GLOAD_LDS16(src, As_ + m * 2048 + sub * 512);                                    \
      } else {                                                                           \
        int q = inst - 12;                                                               \
        const ushort* src = Bp + (size_t)(q * 16 + srow) * CC + (K0) + schunk * 8;       \
        GLOAD_LDS16(src, Bs_ + q * 512);                                                 \
      }                                                                                  \
    }                                                                                    \
  }

  f32x4 acc[3][2][4] = {};
  STAGE_QKV(0, 0)
  __syncthreads();
  for (int s16 = 0; s16 < 16; s16++){
    if (s16 < 15) STAGE_QKV((s16 + 1) & 1, (s16 + 1) * 32)
    const ushort* As = (const ushort*)(smem + (s16 & 1) * 20480);
    const ushort* Bs = As + 6144;
    s16x8 bf[4];
    #pragma unroll
    for (int sn = 0; sn < 4; sn++)
      bf[sn] = *(const s16x8*)&Bs[(wn + sn * 16 + lr) * 32 + xs];
    #pragma unroll
    for (int m = 0; m < 3; m++){
      s16x8 a0 = *(const s16x8*)&As[m * 2048 + (wo + lr) * 32 + xs];
      s16x8 a1 = *(const s16x8*)&As[m * 2048 + (wo + 16 + lr) * 32 + xs];
      #pragma unroll
      for (int sn = 0; sn < 4; sn++){
        acc[m][0][sn] = mfma16(a0, bf[sn], acc[m][0][sn]);
        acc[m][1][sn] = mfma16(a1, bf[sn], acc[m][1][sn]);
      }
    }
    __syncthreads();
  }
#undef STAGE_QKV
  // q, k epilogue: transposed [n][o]
  #pragma unroll
  for (int m = 0; m < 2; m++){
    ushort* dst = (m == 0) ? qo : ko;
    float scl = (m == 0) ? rs : 1.0f;
    #pragma unroll
    for (int so = 0; so < 2; so++)
      #pragma unroll
      for (int sn = 0; sn < 4; sn++){
        int o0 = wo + so * 16 + lk * 4;
        int n  = nb + wn + sn * 16 + lr;
        s16x4 pv;
        #pragma unroll
        for (int r = 0; r < 4; r++) pv[r] = f2bfs((acc[m][so][sn][r] + bl[m][o0 + r]) * scl);
        *reinterpret_cast<s16x4*>(&dst[((size_t)b * NN + n) * CC + ob + o0]) = pv;
      }
  }
  // v epilogue: [o][n] via LDS transpose
  ushort* Ve = (ushort*)smem;   // [64][136]
  #pragma unroll
  for (int so = 0; so < 2; so++)
    #pragma unroll
    for (int sn = 0; sn < 4; sn++){
      int o0 = wo + so * 16 + lk * 4;
      int ncl = wn + sn * 16 + lr;
      #pragma unroll
      for (int r = 0; r < 4; r++) Ve[(o0 + r) * 136 + ncl] = f2bf(acc[2][so][sn][r] + bl[2][o0 + r]);
    }
  __syncthreads();
  {
    int row = t >> 2, cs = (t & 3) * 32;
    ushort* dst = &vo[((size_t)b * CC + ob + row) * NN + nb + cs];
    #pragma unroll
    for (int k = 0; k < 4; k++)
      *(s16x8*)&dst[k * 8] = *(const s16x8*)&Ve[row * 136 + cs + k * 8];
  }
}

// ---------------- S GEMM v5: 256x256, BK=64, dbuf, counted-vmcnt barrier schedule ----------------
__global__ __launch_bounds__(512, 2) void k_gemm_s(const ushort* __restrict__ qt, const ushort* __restrict__ kt,
                                                   ushort* __restrict__ P, float* __restrict__ part){
  extern __shared__ __align__(16) char smem[];
  int lin = blockIdx.x + 16 * blockIdx.y + 256 * blockIdx.z;   // 0..511
  int tt0 = (lin & 7) * 64 + (lin >> 3);
  int jblk = tt0 & 15;
  int pair = tt0 >> 4;          // 0..31
  int b = pair >> 4;            // 0..1
  int j0 = jblk * 256, i0 = (pair & 15) * 256;
  int t = threadIdx.x, w = t >> 6, l = t & 63;
  int lr = l & 15, lk = l >> 4;
  int wj2 = w >> 2, wi4 = w & 3;     // wave tile: j in [wj2*128, +128), i in [wi4*64, +64)
  const ushort* kb = kt + ((size_t)b * NN + j0) * CC;
  const ushort* qb = qt + ((size_t)b * NN + i0) * CC;
  int srow = l >> 3;                       // row within 8-row group
  int schunk = (l & 7) ^ srow;             // swizzled 16B chunk within 128B row

#define STAGE_S(BUF, K0)                                                          \
  {                                                                               \
    ushort* Ks_ = (ushort*)(smem + (BUF) * 32768);                                \
    ushort* Qs_ = (ushort*)(smem + 65536 + (BUF) * 32768);                        \
    _Pragma("unroll")                                                             \
    for (int tt = 0; tt < 8; tt++){                                               \
      int inst = w * 8 + tt;                                                      \
      if (inst < 32){                                                             \
        const ushort* src = kb + (size_t)(inst * 8 + srow) * CC + (K0) + schunk * 8; \
        GLOAD_LDS16(src, Ks_ + inst * 512);                                       \
      } else {                                                                    \
        int g = inst - 32;                                                        \
        const ushort* src = qb + (size_t)(g * 8 + srow) * CC + (K0) + schunk * 8; \
        GLOAD_LDS16(src, Qs_ + g * 512);                                          \
      }                                                                           \
    }                                                                             \
  }

  f32x4 acc[8][4] = {};
  STAGE_S(0, 0)
  for (int s8 = 0; s8 < 8; s8++){
    if (s8 < 7){
      STAGE_S((s8 + 1) & 1, (s8 + 1) * 64)
      asm volatile("s_waitcnt vmcnt(8)" ::: "memory");
    } else {
      asm volatile("s_waitcnt vmcnt(0)" ::: "memory");
    }
    __builtin_amdgcn_s_barrier();
    __builtin_amdgcn_sched_barrier(0);
    const ushort* Ks = (const ushort*)(smem + (s8 & 1) * 32768);
    const ushort* Qs = (const ushort*)(smem + 65536 + (s8 & 1) * 32768);
    #pragma unroll
    for (int kk = 0; kk < 2; kk++){
      int xs = ((kk * 4 + lk) ^ (lr & 7)) * 8;
      s16x8 bf[4];
      #pragma unroll
      for (int si = 0; si < 4; si++)
        bf[si] = *(const s16x8*)&Qs[(wi4 * 64 + si * 16 + lr) * 64 + xs];
      #pragma unroll
      for (int sj = 0; sj < 8; sj++){
        s16x8 a = *(const s16x8*)&Ks[(wj2 * 128 + sj * 16 + lr) * 64 + xs];
        #pragma unroll
        for (int si = 0; si < 4; si++)
          acc[sj][si] = mfma16(a, bf[si], acc[sj][si]);
      }
    }
    asm volatile("s_waitcnt lgkmcnt(0)" ::: "memory");
    __builtin_amdgcn_s_barrier();
    __builtin_amdgcn_sched_barrier(0);
  }
#undef STAGE_S
  // epilogue: exp2 + fused row-sum partials + P write via 2-pass LDS transpose
  ushort* Pe = (ushort*)smem;   // [128 i][264 j] per pass
  float rsum[4] = {0.f, 0.f, 0.f, 0.f};
  #pragma unroll
  for (int pass = 0; pass < 2; pass++){
    if ((wi4 >> 1) == pass){
      #pragma unroll
      for (int sj = 0; sj < 8; sj++)
        #pragma unroll
        for (int si = 0; si < 4; si++){
          int il = (wi4 & 1) * 64 + si * 16 + lr;
          int jl = wj2 * 128 + sj * 16 + lk * 4;
          s16x4 pk;
          #pragma unroll
          for (int r = 0; r < 4; r++){
            float e = __builtin_amdgcn_exp2f(acc[sj][si][r]);
            pk[r] = f2bfs(e);
            rsum[si] += e;
          }
          *(s16x4*)&Pe[il * 264 + jl] = pk;
        }
    }
    __syncthreads();
    {
      int row = t >> 2, cs = (t & 3) * 64;
      ushort* dst = P + ((size_t)b * NN + i0 + pass * 128 + row) * NN + j0 + cs;
      #pragma unroll
      for (int k = 0; k < 8; k++)
        *(s16x8*)&dst[k * 8] = *(const s16x8*)&Pe[row * 264 + cs + k * 8];
    }
    __syncthreads();
  }
  #pragma unroll
  for (int si = 0; si < 4; si++){
    float s = rsum[si];
    s += __shfl_xor(s, 16);
    s += __shfl_xor(s, 32);
    if (lk == 0){
      int il = wi4 * 64 + si * 16 + lr;
      part[((size_t)b * NN + i0 + il) * 32 + jblk * 2 + wj2] = s;
    }
  }
}

// ---------------- combine partial row sums (32/row) -> linv ----------------
__global__ __launch_bounds__(256) void k_rowsum2(const float* __restrict__ part, float* __restrict__ linv){
  int row = blockIdx.x * 4 + (threadIdx.x >> 6);   // 0..8191
  int l = threadIdx.x & 63;
  float s = (l < 32) ? part[(size_t)row * 32 + l] : 0.f;
  #pragma unroll
  for (int off = 32; off; off >>= 1) s += __shfl_down(s, off);
  if (l == 0) linv[row] = 1.0f / s;
}

// ---------------- O GEMM v3: 128i x 128c tile (P re-read 8 -> 4), counted-vmcnt dbuf ----------------
__global__ __launch_bounds__(512) void k_gemm_o(const ushort* __restrict__ P, const ushort* __restrict__ vv,
                                                const float* __restrict__ linv, ushort* __restrict__ ot){
  __shared__ __align__(16) char smem[65536];   // Vs[2][16KB] @0, Ps[2][16KB] @32KB; epilogue Oe [128][136] overlays
  int lin = blockIdx.x + 4 * blockIdx.y + 128 * blockIdx.z;    // 0..255
  int tt0 = (lin & 7) * 32 + (lin >> 3);
  int cblk = tt0 & 3;
  int ib   = tt0 >> 2;          // 0..63
  int b = ib >> 5;
  int c0 = cblk * 128, i0 = (ib & 31) * 128;
  int t = threadIdx.x, w = t >> 6, l = t & 63;
  int lr = l & 15, lk = l >> 4;
  int wi2 = w >> 2, wc4 = w & 3;     // i base wi2*64, c base wc4*32
  const ushort* vb = vv + ((size_t)b * CC + c0) * NN;
  const ushort* pb = P + ((size_t)b * NN + i0) * NN;
  int srow = l >> 3;
  int schunk = (l & 7) ^ srow;

#define STAGE_O(BUF, K0)                                                          \
  {                                                                               \
    ushort* Vs_ = (ushort*)(smem + (BUF) * 16384);                                \
    ushort* Ps_ = (ushort*)(smem + 32768 + (BUF) * 16384);                        \
    _Pragma("unroll")                                                             \
    for (int tt = 0; tt < 4; tt++){                                               \
      int inst = w * 4 + tt;                                                      \
      if (inst < 16){                                                             \
        const ushort* src = vb + (size_t)(inst * 8 + srow) * NN + (K0) + schunk * 8; \
        GLOAD_LDS16(src, Vs_ + inst * 512);                                       \
      } else {                                                                    \
        int g = inst - 16;                                                        \
        const ushort* src = pb + (size_t)(g * 8 + srow) * NN + (K0) + schunk * 8; \
        GLOAD_LDS16(src, Ps_ + g * 512);                                          \
      }                                                                           \
    }                                                                             \
  }

  f32x4 acc[2][4] = {};   // [sc][si]: D[c = wc4*32+sc*16+lk*4+r][i = wi2*64+si*16+lr]
  STAGE_O(0, 0)
  for (int s64 = 0; s64 < 64; s64++){
    if (s64 < 63){
      STAGE_O((s64 + 1) & 1, (s64 + 1) * 64)
      asm volatile("s_waitcnt vmcnt(4)" ::: "memory");
    } else {
      asm volatile("s_waitcnt vmcnt(0)" ::: "memory");
    }
    __builtin_amdgcn_s_barrier();
    __builtin_amdgcn_sched_barrier(0);
    const ushort* Vs = (const ushort*)(smem + (s64 & 1) * 16384);
    const ushort* Ps = (const ushort*)(smem + 32768 + (s64 & 1) * 16384);
    #pragma unroll
    for (int kk = 0; kk < 2; kk++){
      int xs = ((kk * 4 + lk) ^ (lr & 7)) * 8;
      s16x8 af[2], bf[4];
      #pragma unroll
      for (int sc = 0; sc < 2; sc++)
        af[sc] = *(const s16x8*)&Vs[(wc4 * 32 + sc * 16 + lr) * 64 + xs];
      #pragma unroll
      for (int si = 0; si < 4; si++)
        bf[si] = *(const s16x8*)&Ps[(wi2 * 64 + si * 16 + lr) * 64 + xs];
      #pragma unroll
      for (int sc = 0; sc < 2; sc++)
        #pragma unroll
        for (int si = 0; si < 4; si++)
          acc[sc][si] = mfma16(af[sc], bf[si], acc[sc][si]);
    }
    asm volatile("s_waitcnt lgkmcnt(0)" ::: "memory");
    __builtin_amdgcn_s_barrier();
    __builtin_amdgcn_sched_barrier(0);
  }
#undef STAGE_O
  ushort* Oe = (ushort*)smem;   // [128 i][136 c]
  #pragma unroll
  for (int si = 0; si < 4; si++){
    int il = wi2 * 64 + si * 16 + lr;
    float li = linv[(size_t)b * NN + i0 + il];
    #pragma unroll
    for (int sc = 0; sc < 2; sc++){
      int cl = wc4 * 32 + sc * 16 + lk * 4;
      s16x4 pk;
      #pragma unroll
      for (int r = 0; r < 4; r++) pk[r] = f2bfs(acc[sc][si][r] * li);
      *(s16x4*)&Oe[il * 136 + cl] = pk;
    }
  }
  __syncthreads();
  {
    int row = t >> 2, cs = (t & 3) * 32;
    ushort* dst = ot + ((size_t)b * NN + i0 + row) * CC + c0 + cs;
    #pragma unroll
    for (int k = 0; k < 4; k++)
      *(s16x8*)&dst[k * 8] = *(const s16x8*)&Oe[row * 136 + cs + k * 8];
  }
}

// ---------------- proj GEMM v2: 64o x 128n, BK=32, dbuf gload_lds; fp32 out + residual ----------------
__global__ __launch_bounds__(256, 3) void k_gemm_proj2(const ushort* __restrict__ A, const ushort* __restrict__ Bt,
                                                       const float* __restrict__ bias, float* __restrict__ o32,
                                                       const float* __restrict__ xres){
  __shared__ __align__(16) char smem[34048];   // dbuf 2x12KB staging; epilogue trf [64][133] f32 = 34048B
  __shared__ float bl[64];
  int b = blockIdx.z, ob = blockIdx.y * 64, nb = blockIdx.x * 128;
  int t = threadIdx.x, w = t >> 6, l = t & 63;
  int lr = l & 15, lk = l >> 4;
  int wo = (w >> 1) * 32, wn = (w & 1) * 64;
  if (t < 64) bl[t] = bias[ob + t];
  const ushort* Bp = Bt + ((size_t)b * NN + nb) * CC;
  const ushort* Ap = A + (size_t)ob * CC;
  int srow = l >> 2;
  int schunk = (l & 3) ^ ((l >> 2) & 3) ^ ((l >> 4) & 3);
  int xs = (lk ^ (lr & 3) ^ ((lr >> 2) & 3)) * 8;

#define STAGE_P2(BUF, K0)                                                         \
  {                                                                               \
    ushort* As_ = (ushort*)(smem + (BUF) * 12288);                                \
    ushort* Bs_ = As_ + 2048;                                                     \
    _Pragma("unroll")                                                             \
    for (int tt = 0; tt < 3; tt++){                                               \
      int inst = w * 3 + tt;                                                      \
      if (inst < 4){                                                              \
        const ushort* src = Ap + (size_t)(inst * 16 + srow) * CC + (K0) + schunk * 8; \
        GLOAD_LDS16(src, As_ + inst * 512);                                       \
      } else {                                                                    \
        int q = inst - 4;                                                         \
        const ushort* src = Bp + (size_t)(q * 16 + srow) * CC + (K0) + schunk * 8; \
        GLOAD_LDS16(src, Bs_ + q * 512);                                          \
      }                                                                           \
    }                                                                             \
  }

  f32x4 acc[2][4] = {};
  STAGE_P2(0, 0)
  __syncthreads();
  for (int s16 = 0; s16 < 16; s16++){
    if (s16 < 15) STAGE_P2((s16 + 1) & 1, (s16 + 1) * 32)
    const ushort* As = (const ushort*)(smem + (s16 & 1) * 12288);
    const ushort* Bs = As + 2048;
    s16x8 a0 = *(const s16x8*)&As[(wo + lr) * 32 + xs];
    s16x8 a1 = *(const s16x8*)&As[(wo + 16 + lr) * 32 + xs];
    #pragma unroll
    for (int sn = 0; sn < 4; sn++){
      s16x8 bf = *(const s16x8*)&Bs[(wn + sn * 16 + lr) * 32 + xs];
      acc[0][sn] = mfma16(a0, bf, acc[0][sn]);
      acc[1][sn] = mfma16(a1, bf, acc[1][sn]);
    }
    __syncthreads();
  }
#undef STAGE_P2
  float* trf = (float*)smem;   // [64][133]
  #pragma unroll
  for (int so = 0; so < 2; so++)
    #pragma unroll
    for (int sn = 0; sn < 4; sn++){
      int o0 = wo + so * 16 + lk * 4;
      int ncl = wn + sn * 16 + lr;
      #pragma unroll
      for (int r = 0; r < 4; r++) trf[(o0 + r) * 133 + ncl] = acc[so][sn][r] + bl[o0 + r];
    }
  __syncthreads();
  {
    int row = t >> 2, cs = (t & 3) * 32;
    size_t base = ((size_t)b * CC + ob + row) * NN + nb + cs;
    #pragma unroll
    for (int q = 0; q < 8; q++){
      float4 xv = *reinterpret_cast<const float4*>(&xres[base + q * 4]);
      float4 ov;
      ov.x = xv.x + trf[row * 133 + cs + q * 4 + 0];
      ov.y = xv.y + trf[row * 133 + cs + q * 4 + 1];
      ov.z = xv.z + trf[row * 133 + cs + q * 4 + 2];
      ov.w = xv.w + trf[row * 133 + cs + q * 4 + 3];
      *reinterpret_cast<float4*>(&o32[base + q * 4]) = ov;
    }
  }
}

extern "C" void kernel_launch(void* const* d_in, const int* in_sizes, int n_in,
                              void* d_out, int out_size, void* d_ws, size_t ws_size,
                              hipStream_t stream){
  const float* x   = (const float*)d_in[0];
  const float* gsc = (const float*)d_in[1];
  const float* gbi = (const float*)d_in[2];
  const float* wq  = (const float*)d_in[3];
  const float* bq  = (const float*)d_in[4];
  const float* wk  = (const float*)d_in[5];
  const float* bk  = (const float*)d_in[6];
  const float* wv  = (const float*)d_in[7];
  const float* bv  = (const float*)d_in[8];
  const float* wp  = (const float*)d_in[9];
  const float* bp  = (const float*)d_in[10];
  char* ws = (char*)d_ws;
  const size_t MB = 1024 * 1024;
  ushort* wbf  = (ushort*)ws;                    // [0,2MB): bf16 weights q|k|v|proj
  ushort* qtb  = (ushort*)(ws + 2 * MB);         // [2,10): q^T [b][n][c], pre-scaled rs*log2e
  ushort* ktb  = (ushort*)(ws + 10 * MB);        // [10,18): k^T [b][n][c]
  ushort* vvb  = (ushort*)(ws + 18 * MB);        // [18,26): v [b][c][n]
  ushort* hfb  = (ushort*)(ws + 26 * MB);        // [26,34): hf^T, later attn-out [b][n][c]
  ushort* Pbuf = (ushort*)(ws + 34 * MB);        // [34,98): P = exp2(S) bf16 [b][i][j]
  float* linv  = (float*)(ws + 98 * MB);         // [98MB, +32KB)
  float* stats = (float*)(ws + 98 * MB + 64 * 1024);   // 512 B
  float* pstat = (float*)(ws + 98 * MB + 96 * 1024);   // 2 KB partial stats
  float* part  = (float*)(ws + 26 * MB);         // 1MB partials in dead-hf window
  ushort* otb = hfb;

  const float rs = 0.044194173824159216f * 1.4426950408889634f;

  k_convert_w<<<256, 256, 0, stream>>>(wq, wk, wv, wp, wbf);
  k_gn_stats1<<<256, 256, 0, stream>>>(x, pstat);
  k_gn_stats2<<<64, 64, 0, stream>>>(pstat, stats);
  k_gn_apply<<<dim3(128, 2, 1), 256, 0, stream>>>(x, gsc, gbi, stats, hfb);
  k_gemm_qkv2<<<dim3(32, 8, 2), 256, 0, stream>>>(wbf, hfb, bq, bk, bv, qtb, ktb, vvb, rs);
  k_gemm_s<<<dim3(16, 16, 2), 512, 131072, stream>>>(qtb, ktb, Pbuf, part);
  k_rowsum2<<<2048, 256, 0, stream>>>(part, linv);
  k_gemm_o<<<dim3(4, 32, 2), 512, 0, stream>>>(Pbuf, vvb, linv, otb);
  k_gemm_proj2<<<dim3(32, 8, 2), 256, 0, stream>>>(wbf + 3 * CC * CC, otb, bp, (float*)d_out, x);
}